// Round 1
// baseline (311.784 us; speedup 1.0000x reference)
//
#include <hip/hip_runtime.h>
#include <hip/hip_cooperative_groups.h>
#include <math.h>

namespace cg = cooperative_groups;

#define BB   128
#define SS   2048
#define DIN  1024
#define DSRC 1024
#define DOUT 1024
#define WW   64
#define WLEN 129
#define HH   512
#define WCH  17     // w-chunk per score unit; 8 chunks cover 136 >= 129
#define NSPL 4      // split-K factor for all GEMMs

// workspace layout (bytes)
#define OFF_LEN   0
#define OFF_WSI   512
#define OFF_P     1024
#define OFF_XP    4096
#define OFF_X32   (OFF_XP  + NSPL*BB*DSRC*8)   // xp: double[4][128][1024] = 4 MB
#define OFF_Z1P   (OFF_X32 + BB*DSRC*4)        // x32: float[128][1024]
#define OFF_C32   (OFF_Z1P + NSPL*BB*HH*8)     // z1p: double[4][128][512] = 2 MB
#define OFF_OP    (OFF_C32 + BB*DSRC*4)        // c32: float[128][1024]
#define WS_NEED   (OFF_OP  + NSPL*BB*DOUT*4)   // op: float[4][128][1024] = 2 MB (~9.4 MB total)
// aliases: cpart into xp (dead after S2); m/l/spart into z1p (dead after S4)
#define OFF_CPART OFF_XP                       // float[128][8][1024] = 4 MB (exactly xp size)
#define OFF_MPART OFF_Z1P                      // float[128][8]
#define OFF_LPART (OFF_MPART + BB*8*4)
#define OFF_SPART (OFF_LPART + BB*8*4)         // float[128][8][WCH]

// d_out layout (floats)
#define DO_A    (BB*DOUT)
#define DO_WS   (DO_A + BB*WLEN)
#define DO_WE   (DO_WS + BB)

// ---------------- tiled GEMM stage (f32 products, f64 chunk accumulation) ----------------
// 512 threads/block. Each block: 16 output cols (8 waves x 2 j), all 128 rows, K-range = KTOT/NSPL.
// Requires (NTOT/16)*NSPL blocks participating, blk in [0, that).
template<int NTOT, int KTOT, bool F64OUT>
__device__ __forceinline__ void gemm_stage(
    const int blk, const int t,
    const float* __restrict__ A0, const float* __restrict__ A1, const int asplit,
    const int lda, const float* __restrict__ Wt, const int ldw,
    void* __restrict__ outp, float* __restrict__ alds /* [64][130] */)
{
    constexpr int KRANGE = KTOT / NSPL;
    constexpr int NJB = NTOT / 16;
    const int jb = blk % NJB;
    const int ks = blk / NJB;
    const int lane = t & 63;
    const int wvid = __builtin_amdgcn_readfirstlane(t >> 6);
    const int j0 = jb * 16 + wvid * 2;
    const int k0 = ks * KRANGE;

    double dac[2][2];
    dac[0][0] = 0.0; dac[0][1] = 0.0; dac[1][0] = 0.0; dac[1][1] = 0.0;

    const float* wbase = Wt + (size_t)j0 * ldw;

    for (int kc = 0; kc < KRANGE; kc += 64) {
        const int kg = k0 + kc;
        const float* Ab = (kg < asplit) ? (A0 + kg) : (A1 + (kg - asplit));
        __syncthreads();
        #pragma unroll
        for (int q = 0; q < 4; ++q) {
            const int f4 = t + 512 * q;
            const int bb = f4 >> 4, c4 = f4 & 15;
            const float4 v = *reinterpret_cast<const float4*>(Ab + (size_t)bb * lda + c4 * 4);
            alds[(c4*4+0)*130 + bb] = v.x;
            alds[(c4*4+1)*130 + bb] = v.y;
            alds[(c4*4+2)*130 + bb] = v.z;
            alds[(c4*4+3)*130 + bb] = v.w;
        }
        __syncthreads();
        const float* wr = wbase + kg;
        #pragma unroll
        for (int kk16 = 0; kk16 < 64; kk16 += 16) {
            float fa[2][2];
            fa[0][0] = 0.f; fa[0][1] = 0.f; fa[1][0] = 0.f; fa[1][1] = 0.f;
            #pragma unroll
            for (int kk = 0; kk < 16; ++kk) {
                const int k = kk16 + kk;
                const float2 av = *reinterpret_cast<const float2*>(&alds[k*130 + 2*lane]);
                #pragma unroll
                for (int jj = 0; jj < 2; ++jj) {
                    const float wvv = wr[jj*ldw + k];
                    fa[jj][0] = fmaf(wvv, av.x, fa[jj][0]);
                    fa[jj][1] = fmaf(wvv, av.y, fa[jj][1]);
                }
            }
            #pragma unroll
            for (int jj = 0; jj < 2; ++jj) {
                dac[jj][0] += (double)fa[jj][0];
                dac[jj][1] += (double)fa[jj][1];
            }
        }
    }
    #pragma unroll
    for (int i = 0; i < 2; ++i) {
        const int b = 2*lane + i;
        const size_t base = ((size_t)ks * BB + b) * NTOT + j0;
        if constexpr (F64OUT) {
            double* o = (double*)outp;
            o[base + 0] = dac[0][i];
            o[base + 1] = dac[1][i];
        } else {
            float* o = (float*)outp;
            o[base + 0] = (float)dac[0][i];
            o[base + 1] = (float)dac[1][i];
        }
    }
}

// ---------------- fused cooperative kernel: whole pipeline, 7 grid syncs ----------------
__global__ __launch_bounds__(512, 2)
void k_fused(const float* __restrict__ input, const float* __restrict__ src,
             const unsigned char* __restrict__ mask,
             const float* __restrict__ Wi, const float* __restrict__ Wo,
             const float* __restrict__ W1, const float* __restrict__ b1,
             const float* __restrict__ W2, const float* __restrict__ b2,
             float* __restrict__ out, char* __restrict__ ws)
{
    cg::grid_group grid = cg::this_grid();
    const int blk = blockIdx.x;
    const int t = threadIdx.x;

    __shared__ __align__(16) char smem[64*130*4];   // alds / lengths-red / score-red union
    float* alds = (float*)smem;

    int*    lengths = (int*)   (ws + OFF_LEN);
    int*    wsi     = (int*)   (ws + OFF_WSI);
    float*  pbuf    = (float*) (ws + OFF_P);
    double* xp      = (double*)(ws + OFF_XP);
    float*  x32     = (float*) (ws + OFF_X32);
    double* z1p     = (double*)(ws + OFF_Z1P);
    float*  c32     = (float*) (ws + OFF_C32);
    float*  op      = (float*) (ws + OFF_OP);
    float*  cpart   = (float*) (ws + OFF_CPART);
    float*  mpart   = (float*) (ws + OFF_MPART);
    float*  lpart   = (float*) (ws + OFF_LPART);
    float*  spart   = (float*) (ws + OFF_SPART);

    // ---- S1: x = input @ Wi^T  (f64 split-K partials, all 256 blocks) ----
    gemm_stage<1024, 1024, true>(blk, t, input, input, 1<<30, DIN, Wi, DIN, xp, alds);
    grid.sync();

    // ---- S2: reduce xp -> x32 (256*512 threads = 131072 elems) ----
    {
        const int i = blk * 512 + t;
        double s = 0.0;
        #pragma unroll
        for (int ks = 0; ks < NSPL; ++ks) s += xp[(size_t)ks * (BB*DSRC) + i];
        x32[i] = (float)s;
    }
    grid.sync();

    // ---- S3: fc1 partials (blocks 0..127) || lengths (blocks 128..255, otherwise idle) ----
    if (blk < 128) {
        gemm_stage<512, 1024, true>(blk, t, x32, x32, 1<<30, DSRC, W1, DIN, z1p, alds);
    } else {
        const int b = blk - 128;
        const bool is_u8 = (mask[(size_t)SS*BB - 1] != 0);
        int cnt = 0;
        if (is_u8) {
            #pragma unroll
            for (int q = 0; q < 4; ++q)
                cnt += (mask[(size_t)(t + 512*q)*BB + b] != 0) ? 1 : 0;
        } else {
            const int* m32 = (const int*)mask;
            #pragma unroll
            for (int q = 0; q < 4; ++q)
                cnt += (m32[(size_t)(t + 512*q)*BB + b] != 0) ? 1 : 0;
        }
        int* red = (int*)smem;
        red[t] = cnt;
        __syncthreads();
        for (int st = 256; st >= 1; st >>= 1) {
            if (t < st) red[t] += red[t + st];
            __syncthreads();
        }
        if (t == 0) lengths[b] = SS - red[0];
    }
    grid.sync();

    // ---- S4: z1 reduce + tanh + fc2 + sigmoid + p + round (blocks 0..127, 1 wave) ----
    if (blk < 128 && t < 64) {
        const int b = blk, lane = t;
        double part = 0.0;
        #pragma unroll
        for (int q = 0; q < 8; ++q) {
            const int h = lane + 64*q;
            double z = 0.0;
            #pragma unroll
            for (int ks = 0; ks < NSPL; ++ks) z += z1p[((size_t)ks*BB + b)*HH + h];
            z += (double)b1[h];
            part += tanh(z) * (double)W2[h];
        }
        #pragma unroll
        for (int off = 32; off >= 1; off >>= 1) part += __shfl_xor(part, off);
        if (lane == 0) {
            const double z2  = part + (double)b2[0];
            const double sig = 1.0 / (1.0 + exp(-z2));
            const double wsf = (double)lengths[b] * sig;   // p - W
            int W0 = (int)rint(wsf);
            if (W0 < 0) W0 = 0;
            if (W0 > SS - WLEN) W0 = SS - WLEN;
            wsi[b]  = W0;
            pbuf[b] = (float)(wsf + 64.0);
            out[DO_WS + b] = (float)W0;
            out[DO_WE + b] = (float)(W0 + WLEN);
        }
    }
    grid.sync();

    // ---- S5: scores + local softmax + partial c. 1024 (b,wc) units; 2 per block-half x 2 iters ----
    {
        float (*red4)[WCH][4] = (float (*)[WCH][4])smem;
        float (*ssh)[WCH]     = (float (*)[WCH])(smem + 2*WCH*4*sizeof(float));
        const int half = t >> 8, t2 = t & 255;
        const int b = blk >> 1;                 // constant per block
        const int lane = t2 & 63, wv = t2 >> 6;
        const int   w0 = wsi[b];
        const float p  = pbuf[b];
        const int   L  = lengths[b];
        const float4 x4 = *reinterpret_cast<const float4*>(x32 + b*DSRC + 4*t2);
        const int wcbase = (blk & 1) * 4;

        for (int iter = 0; iter < 2; ++iter) {
            const int wc = wcbase + iter*2 + half;
            __syncthreads();                    // protect smem reuse across iters
            float4 sel[WCH];
            #pragma unroll
            for (int i = 0; i < WCH; ++i) {
                const int w = wc*WCH + i;
                if (w < WLEN) {
                    const size_t off = ((size_t)(w0 + w) * BB + b) * DSRC + 4*t2;
                    sel[i] = *reinterpret_cast<const float4*>(src + off);
                } else sel[i] = make_float4(0.f, 0.f, 0.f, 0.f);
            }
            float v[WCH];
            #pragma unroll
            for (int i = 0; i < WCH; ++i)
                v[i] = fmaf(x4.x, sel[i].x, fmaf(x4.y, sel[i].y, fmaf(x4.z, sel[i].z, x4.w * sel[i].w)));
            #pragma unroll
            for (int off = 32; off >= 1; off >>= 1) {
                #pragma unroll
                for (int i = 0; i < WCH; ++i) v[i] += __shfl_xor(v[i], off);
            }
            if (lane == 0) {
                #pragma unroll
                for (int i = 0; i < WCH; ++i) red4[half][i][wv] = v[i];
            }
            __syncthreads();
            if (t2 < WCH) {
                const int w = wc*WCH + t2;
                float s;
                if (w < WLEN) {
                    const float sum = red4[half][t2][0] + red4[half][t2][1]
                                    + red4[half][t2][2] + red4[half][t2][3];
                    const int pos = w0 + w;
                    s = (pos >= WW && pos < L + WW) ? sum : 1e-14f;
                } else s = -INFINITY;
                ssh[half][t2] = s;
            }
            __syncthreads();
            float sv[WCH];
            #pragma unroll
            for (int i = 0; i < WCH; ++i) sv[i] = ssh[half][i];
            float m_loc = -INFINITY;
            #pragma unroll
            for (int i = 0; i < WCH; ++i) m_loc = fmaxf(m_loc, sv[i]);
            float l_loc = 0.f;
            float4 c = make_float4(0.f, 0.f, 0.f, 0.f);
            #pragma unroll
            for (int i = 0; i < WCH; ++i) {
                const float e = expf(sv[i] - m_loc);       // -inf -> 0 for w >= WLEN
                l_loc += e;
                const int w = wc*WCH + i;
                const float d = (float)(w0 + w) - p;
                const float g = expf(d*d * (-1.0f/2048.0f));
                const float wt = e * g;
                c.x = fmaf(wt, sel[i].x, c.x);
                c.y = fmaf(wt, sel[i].y, c.y);
                c.z = fmaf(wt, sel[i].z, c.z);
                c.w = fmaf(wt, sel[i].w, c.w);
            }
            *reinterpret_cast<float4*>(cpart + ((size_t)(b*8 + wc))*DSRC + 4*t2) = c;
            if (t2 == 0) { mpart[b*8 + wc] = m_loc; lpart[b*8 + wc] = l_loc; }
            if (t2 < WCH) spart[(b*8 + wc)*WCH + t2] = ssh[half][t2];
        }
    }
    grid.sync();

    // ---- S6: merge 8 partials per b -> c32 + a output (blocks 0..127) ----
    {
        float* mv = (float*)smem;
        float* lv = (float*)smem + 8;
        if (blk < 128 && t < 8) { mv[t] = mpart[blk*8 + t]; lv[t] = lpart[blk*8 + t]; }
        __syncthreads();
        if (blk < 128) {
            const int b = blk;
            float m = -INFINITY;
            #pragma unroll
            for (int i = 0; i < 8; ++i) m = fmaxf(m, mv[i]);
            float l = 0.f;
            float fac[8];
            #pragma unroll
            for (int i = 0; i < 8; ++i) { fac[i] = expf(mv[i] - m); l = fmaf(lv[i], fac[i], l); }
            const float inv = 1.0f / l;
            float2 c = make_float2(0.f, 0.f);
            #pragma unroll
            for (int i = 0; i < 8; ++i) {
                const float2 cp = *reinterpret_cast<const float2*>(cpart + ((size_t)(b*8 + i))*DSRC + 2*t);
                c.x = fmaf(cp.x, fac[i], c.x);
                c.y = fmaf(cp.y, fac[i], c.y);
            }
            c.x *= inv; c.y *= inv;
            *reinterpret_cast<float2*>(c32 + (size_t)b*DSRC + 2*t) = c;

            if (t < WLEN) {
                const int wc = t / WCH, i = t % WCH;
                const float s = spart[(b*8 + wc)*WCH + i];
                const float d = (float)(wsi[b] + t) - pbuf[b];
                const float g = expf(d*d * (-1.0f/2048.0f));
                out[DO_A + b*WLEN + t] = expf(s - m) * inv * g;
            }
        }
    }
    grid.sync();

    // ---- S7: out partials = concat(c32, input) @ Wo^T (all 256 blocks) ----
    gemm_stage<1024, 2048, false>(blk, t, c32, input, 1024, DSRC, Wo, DIN + DSRC, op, alds);
    grid.sync();

    // ---- S8: reduce op partials + tanh -> out ----
    {
        const int i = blk * 512 + t;
        float s = 0.f;
        #pragma unroll
        for (int ks = 0; ks < NSPL; ++ks) s += op[(size_t)ks * (BB*DOUT) + i];
        out[i] = tanhf(s);
    }
}

extern "C" void kernel_launch(void* const* d_in, const int* in_sizes, int n_in,
                              void* d_out, int out_size, void* d_ws, size_t ws_size,
                              hipStream_t stream)
{
    const float* input = (const float*)d_in[0];
    const float* src   = (const float*)d_in[1];
    const unsigned char* mask = (const unsigned char*)d_in[2];
    const float* Wi = (const float*)d_in[3];
    const float* Wo = (const float*)d_in[4];
    const float* W1 = (const float*)d_in[5];
    const float* b1 = (const float*)d_in[6];
    const float* W2 = (const float*)d_in[7];
    const float* b2 = (const float*)d_in[8];
    float* out = (float*)d_out;
    char* ws = (char*)d_ws;

    if (ws_size < (size_t)WS_NEED) return;

    void* args[] = { (void*)&input, (void*)&src, (void*)&mask, (void*)&Wi, (void*)&Wo,
                     (void*)&W1, (void*)&b1, (void*)&W2, (void*)&b2, (void*)&out, (void*)&ws };
    hipLaunchCooperativeKernel((const void*)k_fused, dim3(256), dim3(512), args, 0, stream);
}

// Round 2
// 118.839 us; speedup vs baseline: 2.6236x; 2.6236x over previous
//
#include <hip/hip_runtime.h>
#include <math.h>

#define BB   128
#define SS   2048
#define DIN  1024
#define DSRC 1024
#define DOUT 1024
#define WW   64
#define WLEN 129
#define HH   512
#define WCH  17     // w-chunk per score block; 8 chunks cover 136 >= 129

// workspace layout (bytes)
#define OFF_WSI   0
#define OFF_P     512
#define OFF_XP    4096                           // xp: double[8][128][1024] = 8 MB
#define OFF_Z1P   (OFF_XP + 8*BB*DSRC*8)         // z1p: double[8][128][512] = 4 MB
#define OFF_CPART (OFF_Z1P + 8*BB*HH*8)          // cpart: float[128][8][1024] = 4 MB
#define OFF_MPART (OFF_CPART + BB*8*DSRC*4)      // mpart: float[128][8]
#define OFF_LPART (OFF_MPART + 4096)
#define OFF_SPART (OFF_LPART + 4096)             // spart: float[128][8][WCH]
#define OFF_OP    (OFF_SPART + BB*8*WCH*4)       // op: float[16][128][1024] = 8 MB
#define WS_NEED   (OFF_OP + 16*BB*DOUT*4)        // ~24.1 MB

// d_out layout (floats)
#define DO_A    (BB*DOUT)        // 131072
#define DO_WS   (DO_A + BB*WLEN) // 147584
#define DO_WE   (DO_WS + BB)     // 147712

// ---------------- K1: generic tiled GEMM (f32 products, f64 chunk accumulation) ----------------
// R0-proven structure: 8 waves x 4 j, lanes hold 2 b (float2), split-K external.
template<int NTOT, int KRANGE, bool F64OUT>
__global__ __launch_bounds__(512)
void k_gemm(const float* __restrict__ A0, const float* __restrict__ A1, int asplit, int lda,
            const float* __restrict__ Wt, int ldw, void* __restrict__ outp)
{
    constexpr int NJB = NTOT / 32;
    const int jb = blockIdx.x % NJB;
    const int ks = blockIdx.x / NJB;
    const int j0 = jb * 32;
    const int k0 = ks * KRANGE;
    const int t  = threadIdx.x;
    const int lane = t & 63;
    const int wvid = __builtin_amdgcn_readfirstlane(t >> 6);

    __shared__ float alds[64][130];

    double dac[4][2];
    #pragma unroll
    for (int jj = 0; jj < 4; ++jj) { dac[jj][0] = 0.0; dac[jj][1] = 0.0; }

    const float* wbase = Wt + (size_t)(j0 + wvid * 4) * ldw;

    for (int kc = 0; kc < KRANGE; kc += 64) {
        const int kg = k0 + kc;
        const float* Ab = (kg < asplit) ? (A0 + kg) : (A1 + (kg - asplit));
        __syncthreads();
        #pragma unroll
        for (int q = 0; q < 4; ++q) {
            int f4 = t + 512 * q;
            int bb = f4 >> 4, c4 = f4 & 15;
            float4 v = *reinterpret_cast<const float4*>(Ab + (size_t)bb * lda + c4 * 4);
            alds[c4*4+0][bb] = v.x;
            alds[c4*4+1][bb] = v.y;
            alds[c4*4+2][bb] = v.z;
            alds[c4*4+3][bb] = v.w;
        }
        __syncthreads();
        const float* wr = wbase + kg;
        #pragma unroll
        for (int kk16 = 0; kk16 < 64; kk16 += 16) {
            float fa[4][2];
            #pragma unroll
            for (int jj = 0; jj < 4; ++jj) { fa[jj][0] = 0.f; fa[jj][1] = 0.f; }
            #pragma unroll
            for (int kk = 0; kk < 16; ++kk) {
                const int k = kk16 + kk;
                float2 av = *reinterpret_cast<const float2*>(&alds[k][2*lane]);
                #pragma unroll
                for (int jj = 0; jj < 4; ++jj) {
                    float wvv = wr[jj*ldw + k];
                    fa[jj][0] = fmaf(wvv, av.x, fa[jj][0]);
                    fa[jj][1] = fmaf(wvv, av.y, fa[jj][1]);
                }
            }
            #pragma unroll
            for (int jj = 0; jj < 4; ++jj) {
                dac[jj][0] += (double)fa[jj][0];
                dac[jj][1] += (double)fa[jj][1];
            }
        }
    }
    #pragma unroll
    for (int i = 0; i < 2; ++i) {
        const int b = 2*lane + i;
        const size_t base = ((size_t)ks * BB + b) * NTOT + j0 + wvid * 4;
        if constexpr (F64OUT) {
            double* o = (double*)outp;
            #pragma unroll
            for (int jj = 0; jj < 4; ++jj) o[base + jj] = dac[jj][i];
        } else {
            float* o = (float*)outp;
            #pragma unroll
            for (int jj = 0; jj < 4; ++jj) o[base + jj] = (float)dac[jj][i];
        }
    }
}

// ---------------- K2: fc1 GEMM, staging A directly from xp (8-way f64 reduce in staging) ----------
// z1p[ks][b][h] partials; x values bit-identical to old x32 (same ks-ascending f64 sum, f32 cast).
__global__ __launch_bounds__(512)
void k_fc1(const double* __restrict__ xp, const float* __restrict__ W1, double* __restrict__ z1p)
{
    constexpr int NTOT = 512, KRANGE = 128, NJB = 16;
    const int jb = blockIdx.x % NJB;
    const int ks = blockIdx.x / NJB;
    const int j0 = jb * 32;
    const int k0 = ks * KRANGE;
    const int t  = threadIdx.x;
    const int lane = t & 63;
    const int wvid = __builtin_amdgcn_readfirstlane(t >> 6);

    __shared__ float alds[64][130];

    double dac[4][2];
    #pragma unroll
    for (int jj = 0; jj < 4; ++jj) { dac[jj][0] = 0.0; dac[jj][1] = 0.0; }

    const float* wbase = W1 + (size_t)(j0 + wvid * 4) * DIN;

    for (int kc = 0; kc < KRANGE; kc += 64) {
        const int kg = k0 + kc;
        __syncthreads();
        #pragma unroll
        for (int q = 0; q < 4; ++q) {
            int f4 = t + 512 * q;
            int bb = f4 >> 4, c4 = f4 & 15;
            const double* base = xp + (size_t)bb * DSRC + kg + c4 * 4;
            double s0 = 0.0, s1 = 0.0, s2 = 0.0, s3 = 0.0;
            #pragma unroll
            for (int ks2 = 0; ks2 < 8; ++ks2) {
                const double* p2 = base + (size_t)ks2 * (BB*DSRC);
                const double2 a = *reinterpret_cast<const double2*>(p2);
                const double2 c = *reinterpret_cast<const double2*>(p2 + 2);
                s0 += a.x; s1 += a.y; s2 += c.x; s3 += c.y;
            }
            alds[c4*4+0][bb] = (float)s0;
            alds[c4*4+1][bb] = (float)s1;
            alds[c4*4+2][bb] = (float)s2;
            alds[c4*4+3][bb] = (float)s3;
        }
        __syncthreads();
        const float* wr = wbase + kg;
        #pragma unroll
        for (int kk16 = 0; kk16 < 64; kk16 += 16) {
            float fa[4][2];
            #pragma unroll
            for (int jj = 0; jj < 4; ++jj) { fa[jj][0] = 0.f; fa[jj][1] = 0.f; }
            #pragma unroll
            for (int kk = 0; kk < 16; ++kk) {
                const int k = kk16 + kk;
                float2 av = *reinterpret_cast<const float2*>(&alds[k][2*lane]);
                #pragma unroll
                for (int jj = 0; jj < 4; ++jj) {
                    float wvv = wr[jj*DIN + k];
                    fa[jj][0] = fmaf(wvv, av.x, fa[jj][0]);
                    fa[jj][1] = fmaf(wvv, av.y, fa[jj][1]);
                }
            }
            #pragma unroll
            for (int jj = 0; jj < 4; ++jj) {
                dac[jj][0] += (double)fa[jj][0];
                dac[jj][1] += (double)fa[jj][1];
            }
        }
    }
    #pragma unroll
    for (int i = 0; i < 2; ++i) {
        const int b = 2*lane + i;
        const size_t base = ((size_t)ks * BB + b) * NTOT + j0 + wvid * 4;
        #pragma unroll
        for (int jj = 0; jj < 4; ++jj) z1p[base + jj] = dac[jj][i];
    }
}

// ---------------- K3: score + fused {lengths, fc2(wsf/W0/p), x4-from-xp} prologue ----------------
// grid (8,128), 256 threads. All 8 wc-blocks of a b compute identical W0/p deterministically.
__global__ __launch_bounds__(256)
void k_score(const double* __restrict__ xp, const float* __restrict__ src,
             const unsigned char* __restrict__ mask,
             const double* __restrict__ z1p, const float* __restrict__ b1,
             const float* __restrict__ W2f, const float* __restrict__ b2,
             int* __restrict__ wsi, float* __restrict__ pbuf,
             float* __restrict__ cpart, float* __restrict__ mpart,
             float* __restrict__ lpart, float* __restrict__ spart)
{
    const int wc = blockIdx.x, b = blockIdx.y;
    const int t = threadIdx.x, lane = t & 63, wv = t >> 6;

    __shared__ int    ired[256];
    __shared__ double dred[256];
    __shared__ float  red[WCH][4];
    __shared__ float  s_sh[WCH];
    __shared__ int    Lsh, W0sh;
    __shared__ float  psh;

    // ---- x4[b, 4t..4t+3] = (float) sum_ks xp  (bit-identical to old x32) ----
    double sx0 = 0.0, sx1 = 0.0, sx2 = 0.0, sx3 = 0.0;
    {
        const double* base = xp + (size_t)b * DSRC + 4 * t;
        #pragma unroll
        for (int ks2 = 0; ks2 < 8; ++ks2) {
            const double* p2 = base + (size_t)ks2 * (BB*DSRC);
            const double2 a = *reinterpret_cast<const double2*>(p2);
            const double2 c = *reinterpret_cast<const double2*>(p2 + 2);
            sx0 += a.x; sx1 += a.y; sx2 += c.x; sx3 += c.y;
        }
    }
    const float4 x4 = make_float4((float)sx0, (float)sx1, (float)sx2, (float)sx3);

    // ---- lengths[b] ----
    {
        const bool is_u8 = (mask[(size_t)SS*BB - 1] != 0);
        int cnt = 0;
        if (is_u8) {
            #pragma unroll
            for (int q = 0; q < 8; ++q)
                cnt += (mask[(size_t)(t + 256*q)*BB + b] != 0) ? 1 : 0;
        } else {
            const int* m32 = (const int*)mask;
            #pragma unroll
            for (int q = 0; q < 8; ++q)
                cnt += (m32[(size_t)(t + 256*q)*BB + b] != 0) ? 1 : 0;
        }
        ired[t] = cnt;
        __syncthreads();
        for (int st = 128; st >= 1; st >>= 1) {
            if (t < st) ired[t] += ired[t + st];
            __syncthreads();
        }
        if (t == 0) Lsh = SS - ired[0];
    }

    // ---- fc2: z1 reduce + tanh + dot(W2) + sigmoid -> W0, p ----
    {
        double part = 0.0;
        #pragma unroll
        for (int hh = 0; hh < 2; ++hh) {
            const int h = t + 256*hh;
            double z = 0.0;
            #pragma unroll
            for (int ks2 = 0; ks2 < 8; ++ks2) z += z1p[((size_t)ks2*BB + b)*HH + h];
            z += (double)b1[h];
            part += tanh(z) * (double)W2f[h];
        }
        dred[t] = part;
        __syncthreads();
        for (int st = 128; st >= 1; st >>= 1) {
            if (t < st) dred[t] += dred[t + st];
            __syncthreads();
        }
        if (t == 0) {
            const double z2  = dred[0] + (double)b2[0];
            const double sig = 1.0 / (1.0 + exp(-z2));
            const double wsf = (double)Lsh * sig;      // p - W
            int W0 = (int)rint(wsf);
            if (W0 < 0) W0 = 0;
            if (W0 > SS - WLEN) W0 = SS - WLEN;
            W0sh = W0;
            psh  = (float)(wsf + 64.0);
            if (wc == 0) { wsi[b] = W0; pbuf[b] = (float)(wsf + 64.0); }
        }
        __syncthreads();
    }
    const int   w0 = W0sh;
    const float p  = psh;
    const int   L  = Lsh;

    // ---- body: identical to R0 k_score ----
    float4 sel[WCH];
    #pragma unroll
    for (int i = 0; i < WCH; ++i) {
        const int w = wc*WCH + i;
        if (w < WLEN) {
            const size_t off = ((size_t)(w0 + w) * BB + b) * DSRC + 4*t;
            sel[i] = *reinterpret_cast<const float4*>(src + off);
        } else sel[i] = make_float4(0.f, 0.f, 0.f, 0.f);
    }

    float v[WCH];
    #pragma unroll
    for (int i = 0; i < WCH; ++i)
        v[i] = fmaf(x4.x, sel[i].x, fmaf(x4.y, sel[i].y, fmaf(x4.z, sel[i].z, x4.w * sel[i].w)));
    #pragma unroll
    for (int off = 32; off >= 1; off >>= 1) {
        #pragma unroll
        for (int i = 0; i < WCH; ++i) v[i] += __shfl_xor(v[i], off);
    }

    if (lane == 0) {
        #pragma unroll
        for (int i = 0; i < WCH; ++i) red[i][wv] = v[i];
    }
    __syncthreads();
    if (t < WCH) {
        const int w = wc*WCH + t;
        float s;
        if (w < WLEN) {
            const float sum = red[t][0] + red[t][1] + red[t][2] + red[t][3];
            const int pos = w0 + t + wc*WCH;
            s = (pos >= WW && pos < L + WW) ? sum : 1e-14f;
        } else s = -INFINITY;
        s_sh[t] = s;
    }
    __syncthreads();

    float sv[WCH];
    #pragma unroll
    for (int i = 0; i < WCH; ++i) sv[i] = s_sh[i];
    float m_loc = -INFINITY;
    #pragma unroll
    for (int i = 0; i < WCH; ++i) m_loc = fmaxf(m_loc, sv[i]);
    float l_loc = 0.f;
    float4 c = make_float4(0.f, 0.f, 0.f, 0.f);
    #pragma unroll
    for (int i = 0; i < WCH; ++i) {
        const float e = expf(sv[i] - m_loc);       // -inf -> 0 for w >= WLEN
        l_loc += e;
        const int w = wc*WCH + i;
        const float d = (float)(w0 + w) - p;
        const float g = expf(d*d * (-1.0f/2048.0f));
        const float wt = e * g;
        c.x = fmaf(wt, sel[i].x, c.x);
        c.y = fmaf(wt, sel[i].y, c.y);
        c.z = fmaf(wt, sel[i].z, c.z);
        c.w = fmaf(wt, sel[i].w, c.w);
    }
    *reinterpret_cast<float4*>(cpart + ((size_t)(b*8 + wc))*DSRC + 4*t) = c;
    if (t == 0) { mpart[b*8 + wc] = m_loc; lpart[b*8 + wc] = l_loc; }
    if (t < WCH) spart[(b*8 + wc)*WCH + t] = s_sh[t];
}

// ---------------- K4: output GEMM, J=8, split-K=16, A c-half merged on-the-fly from cpart ---------
__global__ __launch_bounds__(512)
void k_gemm2m(const float* __restrict__ cpart, const float* __restrict__ mpart,
              const float* __restrict__ lpart, const float* __restrict__ input,
              const float* __restrict__ Wo, float* __restrict__ op)
{
    constexpr int NJB = 16, KRANGE = 128;
    const int jb = blockIdx.x % NJB;
    const int ks = blockIdx.x / NJB;
    const int j0 = jb * 64;
    const int k0 = ks * KRANGE;
    const int t  = threadIdx.x;
    const int lane = t & 63;
    const int wvid = __builtin_amdgcn_readfirstlane(t >> 6);

    __shared__ float alds[64][130];
    __shared__ float fac_s[128][8];
    __shared__ float inv_s[128];

    if (k0 < 1024 && t < 128) {     // fac/inv table, bit-exact replica of k_merge math
        float mv[8], lv[8];
        #pragma unroll
        for (int i = 0; i < 8; ++i) { mv[i] = mpart[t*8 + i]; lv[i] = lpart[t*8 + i]; }
        float m = -INFINITY;
        #pragma unroll
        for (int i = 0; i < 8; ++i) m = fmaxf(m, mv[i]);
        float l = 0.f;
        float fc[8];
        #pragma unroll
        for (int i = 0; i < 8; ++i) { fc[i] = expf(mv[i] - m); l = fmaf(lv[i], fc[i], l); }
        inv_s[t] = 1.0f / l;
        #pragma unroll
        for (int i = 0; i < 8; ++i) fac_s[t][i] = fc[i];
    }

    double dac[8][2];
    #pragma unroll
    for (int jj = 0; jj < 8; ++jj) { dac[jj][0] = 0.0; dac[jj][1] = 0.0; }

    const float* wbase = Wo + (size_t)(j0 + wvid * 8) * (DIN + DSRC);

    for (int kc = 0; kc < KRANGE; kc += 64) {
        const int kg = k0 + kc;
        __syncthreads();
        #pragma unroll
        for (int q = 0; q < 4; ++q) {
            int f4 = t + 512 * q;
            int bb = f4 >> 4, c4 = f4 & 15;
            float4 v;
            if (kg < 1024) {
                const float* cb = cpart + ((size_t)bb * 8) * DSRC + kg + c4 * 4;
                float4 s = make_float4(0.f, 0.f, 0.f, 0.f);
                #pragma unroll
                for (int i = 0; i < 8; ++i) {
                    const float4 cp = *reinterpret_cast<const float4*>(cb + (size_t)i * DSRC);
                    const float f = fac_s[bb][i];
                    s.x = fmaf(cp.x, f, s.x);
                    s.y = fmaf(cp.y, f, s.y);
                    s.z = fmaf(cp.z, f, s.z);
                    s.w = fmaf(cp.w, f, s.w);
                }
                const float iv = inv_s[bb];
                v = make_float4(s.x*iv, s.y*iv, s.z*iv, s.w*iv);
            } else {
                v = *reinterpret_cast<const float4*>(input + (size_t)bb * DIN + (kg - 1024) + c4 * 4);
            }
            alds[c4*4+0][bb] = v.x;
            alds[c4*4+1][bb] = v.y;
            alds[c4*4+2][bb] = v.z;
            alds[c4*4+3][bb] = v.w;
        }
        __syncthreads();
        const float* wr = wbase + kg;
        #pragma unroll
        for (int kk16 = 0; kk16 < 64; kk16 += 16) {
            float fa[8][2];
            #pragma unroll
            for (int jj = 0; jj < 8; ++jj) { fa[jj][0] = 0.f; fa[jj][1] = 0.f; }
            #pragma unroll
            for (int kk = 0; kk < 16; ++kk) {
                const int k = kk16 + kk;
                float2 av = *reinterpret_cast<const float2*>(&alds[k][2*lane]);
                #pragma unroll
                for (int jj = 0; jj < 8; ++jj) {
                    float wvv = wr[(size_t)jj*(DIN+DSRC) + k];
                    fa[jj][0] = fmaf(wvv, av.x, fa[jj][0]);
                    fa[jj][1] = fmaf(wvv, av.y, fa[jj][1]);
                }
            }
            #pragma unroll
            for (int jj = 0; jj < 8; ++jj) {
                dac[jj][0] += (double)fa[jj][0];
                dac[jj][1] += (double)fa[jj][1];
            }
        }
    }
    #pragma unroll
    for (int i = 0; i < 2; ++i) {
        const int b = 2*lane + i;
        const size_t base = ((size_t)ks * BB + b) * DOUT + j0 + wvid * 8;
        #pragma unroll
        for (int jj = 0; jj < 8; ++jj) op[base + jj] = (float)dac[jj][i];
    }
}

// ---------------- K5: flat epilogue: out-reduce+tanh | a-output | ws/we ----------------
__global__ __launch_bounds__(512)
void k_epi(const float* __restrict__ op, const float* __restrict__ mpart,
           const float* __restrict__ lpart, const float* __restrict__ spart,
           const int* __restrict__ wsi, const float* __restrict__ pbuf,
           float* __restrict__ out)
{
    const int idx = blockIdx.x * 512 + threadIdx.x;
    if (idx < BB*DOUT) {
        float s = 0.f;
        #pragma unroll
        for (int ks = 0; ks < 16; ++ks) s += op[(size_t)ks * (BB*DOUT) + idx];
        out[idx] = tanhf(s);
    } else if (idx < BB*DOUT + BB*WLEN) {
        const int j = idx - BB*DOUT;
        const int b = j / WLEN, w = j - b*WLEN;
        float mv[8], lv[8];
        #pragma unroll
        for (int i = 0; i < 8; ++i) { mv[i] = mpart[b*8 + i]; lv[i] = lpart[b*8 + i]; }
        float m = -INFINITY;
        #pragma unroll
        for (int i = 0; i < 8; ++i) m = fmaxf(m, mv[i]);
        float l = 0.f;
        #pragma unroll
        for (int i = 0; i < 8; ++i) { const float f = expf(mv[i] - m); l = fmaf(lv[i], f, l); }
        const float inv = 1.0f / l;
        const int wc = w / WCH, i2 = w - wc*WCH;
        const float s = spart[(b*8 + wc)*WCH + i2];
        const float d = (float)(wsi[b] + w) - pbuf[b];
        const float g = expf(d*d * (-1.0f/2048.0f));
        out[DO_A + j] = expf(s - m) * inv * g;
    } else if (idx < BB*DOUT + BB*WLEN + 2*BB) {
        const int k = idx - BB*DOUT - BB*WLEN;
        const int b = k & 127, hi = k >> 7;
        out[(hi ? DO_WE : DO_WS) + b] = (float)(wsi[b] + (hi ? WLEN : 0));
    }
}

extern "C" void kernel_launch(void* const* d_in, const int* in_sizes, int n_in,
                              void* d_out, int out_size, void* d_ws, size_t ws_size,
                              hipStream_t stream)
{
    const float* input = (const float*)d_in[0];
    const float* src   = (const float*)d_in[1];
    const unsigned char* mask = (const unsigned char*)d_in[2];
    const float* Wi = (const float*)d_in[3];
    const float* Wo = (const float*)d_in[4];
    const float* W1 = (const float*)d_in[5];
    const float* b1 = (const float*)d_in[6];
    const float* W2 = (const float*)d_in[7];
    const float* b2 = (const float*)d_in[8];
    float* out = (float*)d_out;

    if (ws_size < (size_t)WS_NEED) return;

    char* ws = (char*)d_ws;
    int*    wsi   = (int*)   (ws + OFF_WSI);
    float*  pbuf  = (float*) (ws + OFF_P);
    double* xp    = (double*)(ws + OFF_XP);
    double* z1p   = (double*)(ws + OFF_Z1P);
    float*  cpart = (float*) (ws + OFF_CPART);
    float*  mpart = (float*) (ws + OFF_MPART);
    float*  lpart = (float*) (ws + OFF_LPART);
    float*  spart = (float*) (ws + OFF_SPART);
    float*  op    = (float*) (ws + OFF_OP);

    // K1: x partials = input @ Wi^T (split-K=8, f64 partials)
    k_gemm<1024,128,true><<<256, 512, 0, stream>>>(input, input, 1<<30, DIN, Wi, DIN, xp);
    // K2: z1 partials = x @ W1^T (stages A from xp with in-staging f64 reduce)
    k_fc1<<<128, 512, 0, stream>>>(xp, W1, z1p);
    // K3: score + fused lengths/fc2/x4 prologue
    k_score<<<dim3(8,128), 256, 0, stream>>>(xp, src, mask, z1p, b1, W2, b2,
                                             wsi, pbuf, cpart, mpart, lpart, spart);
    // K4: out partials = concat(c, input) @ Wo^T with merge fused into staging
    k_gemm2m<<<256, 512, 0, stream>>>(cpart, mpart, lpart, input, Wo, op);
    // K5: epilogue: reduce+tanh, a, ws/we
    k_epi<<<289, 512, 0, stream>>>(op, mpart, lpart, spart, wsi, pbuf, out);
}

// Round 3
// 75.656 us; speedup vs baseline: 4.1210x; 1.5708x over previous
//
#include <hip/hip_runtime.h>
#include <math.h>

#define BB   128
#define SS   2048
#define DIN  1024
#define DSRC 1024
#define DOUT 1024
#define WW   64
#define WLEN 129
#define HH   512
#define WCH  17     // w-chunk per score block; 8 chunks cover 136 >= 129
#define GW   136    // gaussian table width (WLEN padded)

// workspace layout (bytes)
#define OFF_WSI   0
#define OFF_P     512
#define OFF_LEN   1024
#define OFF_GTAB  4096        // float[128][136]
#define OFF_XP    73728       // double[4][128][1024] = 4 MB
#define OFF_X32   4268032     // float[128][1024]
#define OFF_Z1P   4792320     // double[4][128][512] = 2 MB
#define OFF_C32   6889472     // float[128][1024]
#define OFF_CPART 7413760     // float[128][8][1024] = 4 MB
#define OFF_MPART 11608064
#define OFF_LPART 11612160
#define OFF_SPART 11616256    // float[128][8][WCH]
#define OFF_OP    11685888    // float[8][128][1024] = 4 MB
#define WS_NEED   15880192

// d_out layout (floats)
#define DO_A    (BB*DOUT)        // 131072
#define DO_WS   (DO_A + BB*WLEN) // 147584
#define DO_WE   (DO_WS + BB)     // 147712

// ---------------- 16-col tiled GEMM stage (f32 products, f64 chunk accumulation) ----------------
// R1-validated geometry: NJB = NTOT/16 j-blocks, 4 splits, 8 waves x 2 cols, lanes hold 2 b rows.
template<int NTOT, int KRANGE, bool F64OUT>
__device__ __forceinline__ void gemm16(const int gblk, const int t,
    const float* __restrict__ A, const int lda,
    const float* __restrict__ Wt, const int ldw,
    void* __restrict__ outp, float* __restrict__ alds /* [64][130] */)
{
    constexpr int NJB = NTOT / 16;
    const int jb = gblk % NJB;
    const int ks = gblk / NJB;
    const int lane = t & 63;
    const int wvid = __builtin_amdgcn_readfirstlane(t >> 6);
    const int j0 = jb * 16 + wvid * 2;
    const int k0 = ks * KRANGE;

    double dac[2][2];
    dac[0][0] = 0.0; dac[0][1] = 0.0; dac[1][0] = 0.0; dac[1][1] = 0.0;

    const float* wbase = Wt + (size_t)j0 * ldw;

    for (int kc = 0; kc < KRANGE; kc += 64) {
        const int kg = k0 + kc;
        __syncthreads();
        #pragma unroll
        for (int q = 0; q < 4; ++q) {
            const int f4 = t + 512 * q;
            const int bb = f4 >> 4, c4 = f4 & 15;
            const float4 v = *reinterpret_cast<const float4*>(A + (size_t)bb * lda + kg + c4 * 4);
            alds[(c4*4+0)*130 + bb] = v.x;
            alds[(c4*4+1)*130 + bb] = v.y;
            alds[(c4*4+2)*130 + bb] = v.z;
            alds[(c4*4+3)*130 + bb] = v.w;
        }
        __syncthreads();
        const float* wr = wbase + kg;
        #pragma unroll
        for (int kk16 = 0; kk16 < 64; kk16 += 16) {
            float fa[2][2];
            fa[0][0] = 0.f; fa[0][1] = 0.f; fa[1][0] = 0.f; fa[1][1] = 0.f;
            #pragma unroll
            for (int kk = 0; kk < 16; ++kk) {
                const int k = kk16 + kk;
                const float2 av = *reinterpret_cast<const float2*>(&alds[k*130 + 2*lane]);
                #pragma unroll
                for (int jj = 0; jj < 2; ++jj) {
                    const float wvv = wr[jj*ldw + k];
                    fa[jj][0] = fmaf(wvv, av.x, fa[jj][0]);
                    fa[jj][1] = fmaf(wvv, av.y, fa[jj][1]);
                }
            }
            #pragma unroll
            for (int jj = 0; jj < 2; ++jj) {
                dac[jj][0] += (double)fa[jj][0];
                dac[jj][1] += (double)fa[jj][1];
            }
        }
    }
    #pragma unroll
    for (int i = 0; i < 2; ++i) {
        const int b = 2*lane + i;
        const size_t base = ((size_t)ks * BB + b) * NTOT + j0;
        if constexpr (F64OUT) {
            double* o = (double*)outp;
            o[base + 0] = dac[0][i];
            o[base + 1] = dac[1][i];
        } else {
            float* o = (float*)outp;
            o[base + 0] = (float)dac[0][i];
            o[base + 1] = (float)dac[1][i];
        }
    }
}

// ---------------- K1: combo = gemm1 (256) | gemm2-input-half (256) | lengths (128) ----------------
__global__ __launch_bounds__(512)
void k_combo(const float* __restrict__ input, const float* __restrict__ Wi,
             const float* __restrict__ Wo, const unsigned char* __restrict__ mask,
             double* __restrict__ xp, float* __restrict__ op4, int* __restrict__ lengths)
{
    __shared__ __align__(16) float alds[64*130];
    const int blk = blockIdx.x, t = threadIdx.x;
    if (blk < 256) {
        // x partials = input @ Wi^T  (f64 partials, 4 splits)
        gemm16<1024, 256, true>(blk, t, input, DIN, Wi, DIN, xp, alds);
    } else if (blk < 512) {
        // op[4..7] = input @ Wo[:,1024:]^T  (independent of everything downstream)
        gemm16<1024, 256, false>(blk - 256, t, input, DIN, Wo + 1024, DIN + DSRC, op4, alds);
    } else {
        const int b = blk - 512;
        const bool is_u8 = (mask[(size_t)SS*BB - 1] != 0);
        int cnt = 0;
        if (is_u8) {
            #pragma unroll
            for (int q = 0; q < 4; ++q)
                cnt += (mask[(size_t)(t + 512*q)*BB + b] != 0) ? 1 : 0;
        } else {
            const int* m32 = (const int*)mask;
            #pragma unroll
            for (int q = 0; q < 4; ++q)
                cnt += (m32[(size_t)(t + 512*q)*BB + b] != 0) ? 1 : 0;
        }
        int* red = (int*)alds;
        red[t] = cnt;
        __syncthreads();
        for (int st = 256; st >= 1; st >>= 1) {
            if (t < st) red[t] += red[t + st];
            __syncthreads();
        }
        if (t == 0) lengths[b] = SS - red[0];
    }
}

// ---------------- K2: reduce xp (4 f64 partials) -> x32 ----------------
__global__ __launch_bounds__(512)
void k_xred(const double* __restrict__ xp, float* __restrict__ x32)
{
    const int i = blockIdx.x * 512 + threadIdx.x;
    double s = 0.0;
    #pragma unroll
    for (int ks = 0; ks < 4; ++ks) s += xp[(size_t)ks * (BB*DSRC) + i];
    x32[i] = (float)s;
}

// ---------------- K3: fc1 partials = x32 @ W1^T ----------------
__global__ __launch_bounds__(512)
void k_fc1(const float* __restrict__ x32, const float* __restrict__ W1, double* __restrict__ z1p)
{
    __shared__ __align__(16) float alds[64*130];
    gemm16<512, 256, true>(blockIdx.x, threadIdx.x, x32, DSRC, W1, DIN, z1p, alds);
}

// ---------------- K4: fc2: z1 reduce + tanh + dot(W2) + sigmoid -> W0, p, gtab, ws/we ------------
__global__ __launch_bounds__(64)
void k_fc2(const double* __restrict__ z1p, const float* __restrict__ b1,
           const float* __restrict__ W2f, const float* __restrict__ b2,
           const int* __restrict__ lengths, int* __restrict__ wsi,
           float* __restrict__ pbuf, float* __restrict__ gtab, float* __restrict__ dout)
{
    const int b = blockIdx.x, lane = threadIdx.x;
    double part = 0.0;
    #pragma unroll
    for (int q = 0; q < 8; ++q) {
        const int h = lane + 64*q;
        double z = 0.0;
        #pragma unroll
        for (int ks = 0; ks < 4; ++ks) z += z1p[((size_t)ks*BB + b)*HH + h];
        z += (double)b1[h];
        part += tanh(z) * (double)W2f[h];
    }
    #pragma unroll
    for (int off = 32; off >= 1; off >>= 1) part += __shfl_xor(part, off);
    // all lanes now hold the full sum -> replicate the (deterministic) f64 tail
    const double z2  = part + (double)b2[0];
    const double sig = 1.0 / (1.0 + exp(-z2));
    const double wsf = (double)lengths[b] * sig;   // p - W
    int W0 = (int)rint(wsf);
    if (W0 < 0) W0 = 0;
    if (W0 > SS - WLEN) W0 = SS - WLEN;
    const float pf = (float)(wsf + 64.0);
    if (lane == 0) {
        wsi[b]  = W0;
        pbuf[b] = pf;
        dout[DO_WS + b] = (float)W0;
        dout[DO_WE + b] = (float)(W0 + WLEN);
    }
    #pragma unroll
    for (int q = 0; q < 3; ++q) {
        const int w = lane + 64*q;
        if (w < GW) {
            float g = 0.f;
            if (w < WLEN) {
                const float d = (float)(W0 + w) - pf;
                g = expf(d*d * (-1.0f/2048.0f));
            }
            gtab[b*GW + w] = g;
        }
    }
}

// ---------------- K5: per-(b, w-chunk) scores + local softmax + partial c ----------------
// grid (8, 128), 256 threads. Multi-value butterfly: 32 shuffle-adds instead of 102.
__global__ __launch_bounds__(256)
void k_score(const float* __restrict__ x32, const float* __restrict__ src,
             const int* __restrict__ wsi, const float* __restrict__ pbuf,
             const int* __restrict__ lengths, const float* __restrict__ gtab,
             float* __restrict__ cpart, float* __restrict__ mpart,
             float* __restrict__ lpart, float* __restrict__ spart)
{
    const int wc = blockIdx.x, b = blockIdx.y;
    const int t = threadIdx.x, lane = t & 63, wv = t >> 6;
    const int   w0 = wsi[b];
    const int   L  = lengths[b];

    const float4 x4 = *reinterpret_cast<const float4*>(x32 + b*DSRC + 4*t);

    float4 sel[WCH];
    #pragma unroll
    for (int i = 0; i < WCH; ++i) {
        const int w = wc*WCH + i;
        if (w < WLEN) {
            const size_t off = ((size_t)(w0 + w) * BB + b) * DSRC + 4*t;
            sel[i] = *reinterpret_cast<const float4*>(src + off);
        } else sel[i] = make_float4(0.f, 0.f, 0.f, 0.f);
    }

    // per-lane partial dot for each of 17 rows
    float w_[32];
    #pragma unroll
    for (int i = 0; i < WCH; ++i)
        w_[i] = fmaf(x4.x, sel[i].x, fmaf(x4.y, sel[i].y, fmaf(x4.z, sel[i].z, x4.w * sel[i].w)));
    #pragma unroll
    for (int i = WCH; i < 32; ++i) w_[i] = 0.f;

    // multi-value butterfly: after 5 levels lane holds value (lane&31) summed over its 32-lane half
    #pragma unroll
    for (int k = 0; k < 5; ++k) {
        const int dist = 1 << k;
        const bool hi = (lane >> k) & 1;
        const int n2 = 32 >> (k + 1);
        #pragma unroll
        for (int i = 0; i < n2; ++i) {
            const float keep = hi ? w_[2*i+1] : w_[2*i];
            const float send = hi ? w_[2*i]   : w_[2*i+1];
            w_[i] = keep + __shfl_xor(send, dist);
        }
    }
    const float tot = w_[0] + __shfl_xor(w_[0], 32);   // full 64-lane sum of row (lane&31)

    __shared__ float red[WCH][4];
    __shared__ float s_sh[WCH];
    if (lane < WCH) red[lane][wv] = tot;
    __syncthreads();
    if (t < WCH) {
        const int w = wc*WCH + t;
        float s;
        if (w < WLEN) {
            const float sum = red[t][0] + red[t][1] + red[t][2] + red[t][3];
            const int pos = w0 + w;
            s = (pos >= WW && pos < L + WW) ? sum : 1e-14f;
        } else s = -INFINITY;
        s_sh[t] = s;
    }
    __syncthreads();

    float sv[WCH];
    #pragma unroll
    for (int i = 0; i < WCH; ++i) sv[i] = s_sh[i];
    float m_loc = -INFINITY;
    #pragma unroll
    for (int i = 0; i < WCH; ++i) m_loc = fmaxf(m_loc, sv[i]);
    float l_loc = 0.f;
    float4 c = make_float4(0.f, 0.f, 0.f, 0.f);
    #pragma unroll
    for (int i = 0; i < WCH; ++i) {
        const float e = expf(sv[i] - m_loc);       // -inf -> 0 for w >= WLEN
        l_loc += e;
        const float g = gtab[b*GW + wc*WCH + i];   // 0 beyond WLEN
        const float wt = e * g;
        c.x = fmaf(wt, sel[i].x, c.x);
        c.y = fmaf(wt, sel[i].y, c.y);
        c.z = fmaf(wt, sel[i].z, c.z);
        c.w = fmaf(wt, sel[i].w, c.w);
    }
    *reinterpret_cast<float4*>(cpart + ((size_t)(b*8 + wc))*DSRC + 4*t) = c;
    if (t == 0) { mpart[b*8 + wc] = m_loc; lpart[b*8 + wc] = l_loc; }
    if (t < WCH) spart[(b*8 + wc)*WCH + t] = s_sh[t];
}

// ---------------- K6: merge 8 partials per b -> c32 + a output ----------------
__global__ __launch_bounds__(256)
void k_merge(const float* __restrict__ cpart, const float* __restrict__ mpart,
             const float* __restrict__ lpart, const float* __restrict__ spart,
             const float* __restrict__ gtab, float* __restrict__ c32,
             float* __restrict__ dout)
{
    const int b = blockIdx.x, t = threadIdx.x;
    __shared__ float mv[8], lv[8];
    if (t < 8) { mv[t] = mpart[b*8 + t]; lv[t] = lpart[b*8 + t]; }
    __syncthreads();
    float m = -INFINITY;
    #pragma unroll
    for (int i = 0; i < 8; ++i) m = fmaxf(m, mv[i]);
    float l = 0.f;
    float fac[8];
    #pragma unroll
    for (int i = 0; i < 8; ++i) { fac[i] = expf(mv[i] - m); l = fmaf(lv[i], fac[i], l); }
    const float inv = 1.0f / l;

    float4 c = make_float4(0.f, 0.f, 0.f, 0.f);
    #pragma unroll
    for (int i = 0; i < 8; ++i) {
        const float4 cp = *reinterpret_cast<const float4*>(cpart + ((size_t)(b*8 + i))*DSRC + 4*t);
        c.x = fmaf(cp.x, fac[i], c.x);
        c.y = fmaf(cp.y, fac[i], c.y);
        c.z = fmaf(cp.z, fac[i], c.z);
        c.w = fmaf(cp.w, fac[i], c.w);
    }
    c.x *= inv; c.y *= inv; c.z *= inv; c.w *= inv;
    *reinterpret_cast<float4*>(c32 + (size_t)b*DSRC + 4*t) = c;

    if (t < WLEN) {
        const int wc = t / WCH, i = t % WCH;
        const float s = spart[(b*8 + wc)*WCH + i];
        const float g = gtab[b*GW + t];
        dout[DO_A + b*WLEN + t] = expf(s - m) * inv * g;
    }
}

// ---------------- K7: op[0..3] = c32 @ Wo[:, :1024]^T ----------------
__global__ __launch_bounds__(512)
void k_gemm2c(const float* __restrict__ c32, const float* __restrict__ Wo, float* __restrict__ op)
{
    __shared__ __align__(16) float alds[64*130];
    gemm16<1024, 256, false>(blockIdx.x, threadIdx.x, c32, DSRC, Wo, DIN + DSRC, op, alds);
}

// ---------------- K8: reduce 8 op partials + tanh -> out ----------------
__global__ __launch_bounds__(512)
void k_outred(const float* __restrict__ op, float* __restrict__ dout)
{
    const int i = blockIdx.x * 512 + threadIdx.x;
    float s = 0.f;
    #pragma unroll
    for (int ks = 0; ks < 8; ++ks) s += op[(size_t)ks * (BB*DOUT) + i];
    dout[i] = tanhf(s);
}

extern "C" void kernel_launch(void* const* d_in, const int* in_sizes, int n_in,
                              void* d_out, int out_size, void* d_ws, size_t ws_size,
                              hipStream_t stream)
{
    const float* input = (const float*)d_in[0];
    const float* src   = (const float*)d_in[1];
    const unsigned char* mask = (const unsigned char*)d_in[2];
    const float* Wi = (const float*)d_in[3];
    const float* Wo = (const float*)d_in[4];
    const float* W1 = (const float*)d_in[5];
    const float* b1 = (const float*)d_in[6];
    const float* W2 = (const float*)d_in[7];
    const float* b2 = (const float*)d_in[8];
    float* out = (float*)d_out;

    if (ws_size < (size_t)WS_NEED) return;

    char* ws = (char*)d_ws;
    int*    wsi     = (int*)   (ws + OFF_WSI);
    float*  pbuf    = (float*) (ws + OFF_P);
    int*    lengths = (int*)   (ws + OFF_LEN);
    float*  gtab    = (float*) (ws + OFF_GTAB);
    double* xp      = (double*)(ws + OFF_XP);
    float*  x32     = (float*) (ws + OFF_X32);
    double* z1p     = (double*)(ws + OFF_Z1P);
    float*  c32     = (float*) (ws + OFF_C32);
    float*  cpart   = (float*) (ws + OFF_CPART);
    float*  mpart   = (float*) (ws + OFF_MPART);
    float*  lpart   = (float*) (ws + OFF_LPART);
    float*  spart   = (float*) (ws + OFF_SPART);
    float*  op      = (float*) (ws + OFF_OP);

    // L1: gemm1 || gemm2-input-half || lengths  (all mutually independent)
    k_combo<<<640, 512, 0, stream>>>(input, Wi, Wo, mask, xp, op + 4*(size_t)BB*DOUT, lengths);
    // L2: x32 = f64-reduce(xp)
    k_xred<<<256, 512, 0, stream>>>(xp, x32);
    // L3: z1 partials = x32 @ W1^T
    k_fc1<<<128, 512, 0, stream>>>(x32, W1, z1p);
    // L4: fc2 -> W0/p/gtab/ws/we
    k_fc2<<<128, 64, 0, stream>>>(z1p, b1, W2, b2, lengths, wsi, pbuf, gtab, out);
    // L5: scores + local softmax + partial c
    k_score<<<dim3(8,128), 256, 0, stream>>>(x32, src, wsi, pbuf, lengths, gtab,
                                             cpart, mpart, lpart, spart);
    // L6: merge partials -> c32 + a
    k_merge<<<128, 256, 0, stream>>>(cpart, mpart, lpart, spart, gtab, c32, out);
    // L7: op[0..3] = c32 @ Wo_c^T
    k_gemm2c<<<256, 512, 0, stream>>>(c32, Wo, op);
    // L8: out = tanh(sum op)
    k_outred<<<256, 512, 0, stream>>>(op, out);
}